// Round 4
// baseline (4851.200 us; speedup 1.0000x reference)
//
#include <hip/hip_runtime.h>
#include <hip/hip_bf16.h>
#include <hip/hip_cooperative_groups.h>

namespace cg = cooperative_groups;

#define VOCAB 29
#define VEC   512
#define HID   1024
#define SEN   64
#define BATCH 2048

typedef __bf16 bf16_t;
typedef bf16_t bf16x8 __attribute__((ext_vector_type(8)));
typedef float  floatx4 __attribute__((ext_vector_type(4)));

// ---------------- prep: W_hh fp32 -> bf16 ----------------
__global__ void cvt_whh(const float* __restrict__ w, bf16_t* __restrict__ o, int n) {
    int i = blockIdx.x * blockDim.x + threadIdx.x;
    if (i < n) o[i] = (bf16_t)w[i];
}

// ---------------- prep: W_cls fp32 [65][1024] -> bf16 padded [80][1024] ----------------
__global__ void cvt_wcls(const float* __restrict__ w, bf16_t* __restrict__ o) {
    int i = blockIdx.x * blockDim.x + threadIdx.x;
    if (i >= 80 * HID) return;
    o[i] = (i < 65 * HID) ? (bf16_t)w[i] : (bf16_t)0.0f;
}

// ---------------- prep: proj[v][h] = dot(emb[v], W_ih[h]) (fp32) ----------------
__global__ void proj_kernel(const float* __restrict__ emb, const float* __restrict__ wih,
                            float* __restrict__ proj) {
    int idx = blockIdx.x * blockDim.x + threadIdx.x;
    if (idx >= VOCAB * HID) return;
    int v = idx / HID, h = idx % HID;
    const float* e = emb + v * VEC;
    const float* w = wih + h * VEC;
    float s = 0.f;
    for (int k = 0; k < VEC; k += 4) {
        float4 ev = *(const float4*)(e + k);
        float4 wv = *(const float4*)(w + k);
        s += ev.x * wv.x + ev.y * wv.y + ev.z * wv.z + ev.w * wv.w;
    }
    proj[idx] = s;
}

// exact identity tanh(x) = 1 - 2/(exp(2x)+1); fp32 rounding error << bf16 ulp
__device__ __forceinline__ float fast_tanh(float x) {
    float e = __expf(2.0f * x);
    return 1.0f - 2.0f / (e + 1.0f);
}

// =====================================================================
// FAST PATH: persistent cooperative kernel, all 64 steps, grid (16,16),
// 128 threads = 2 waves, wave tile 64x64 (4x4 frags of 16x16x32 bf16).
// A and B fragments both stream global->VGPR (L2-resident), 3-deep
// register pipeline, ZERO intra-step barriers. LDS: proj slice + tokens
// only (~40 KB, safely under any per-workgroup limit).
// =====================================================================
__global__ __launch_bounds__(128, 1)
void rnn_stream(const bf16_t* __restrict__ whh_bf, const float* __restrict__ proj,
                const int* __restrict__ x, bf16_t* __restrict__ h0b, bf16_t* __restrict__ h1b)
{
    __shared__ float proj_sh[VOCAB][64];   // 7.25 KB
    __shared__ int   tok_sh[128][SEN];     // 32 KB

    const int tid  = threadIdx.x;
    const int m0   = blockIdx.x * 128;
    const int n0   = blockIdx.y * 64;
    const int wave = tid >> 6;
    const int lane = tid & 63;
    const int wm   = wave * 64;       // 2 waves split m: block tile 128m x 64n
    const int q    = lane >> 4;
    const int l16  = lane & 15;

    // one-time: proj slice -> LDS
    for (int i = tid; i < VOCAB * 64; i += 128) {
        int v = i >> 6, j = i & 63;
        proj_sh[v][j] = proj[v * HID + n0 + j];
    }
    // one-time: this block's 128 token rows -> LDS (int4 loads)
    {
        int r = tid;  // 128 threads = 128 rows
        const int4* src = (const int4*)&x[(m0 + r) * SEN];
#pragma unroll
        for (int c = 0; c < SEN / 4; c++) ((int4*)&tok_sh[r][0])[c] = src[c];
    }
    __syncthreads();

    // per-lane base element offsets (verified frag mapping: row=l16, k=q*8+j)
    int offA[4], offB[4];
#pragma unroll
    for (int mi = 0; mi < 4; mi++) offA[mi] = (m0 + wm + mi * 16 + l16) * HID + q * 8;
#pragma unroll
    for (int ni = 0; ni < 4; ni++) offB[ni] = (n0 + ni * 16 + l16) * HID + q * 8;

    cg::grid_group grid = cg::this_grid();

    for (int t = 0; t < SEN; t++) {
        const bf16_t* __restrict__ hin  = (t & 1) ? h0b : h1b;
        bf16_t* __restrict__       hout = (t & 1) ? h1b : h0b;

        floatx4 acc[4][4];
#pragma unroll
        for (int i = 0; i < 4; i++)
#pragma unroll
            for (int j = 0; j < 4; j++) acc[i][j] = (floatx4){0.f, 0.f, 0.f, 0.f};

        if (t > 0) {
            // 3-deep register pipeline over 32 k-steps (prefetch distance 2)
            bf16x8 af[3][4], bfr[3][4];
#pragma unroll
            for (int s = 0; s < 2; s++) {
#pragma unroll
                for (int i = 0; i < 4; i++) {
                    af[s][i]  = *(const bf16x8*)&hin[offA[i] + s * 32];
                    bfr[s][i] = *(const bf16x8*)&whh_bf[offB[i] + s * 32];
                }
            }
#pragma unroll
            for (int ks = 0; ks < 32; ks++) {
                const int cur = ks % 3;
                const int nxt = (ks + 2) % 3;
                if (ks < 30) {
#pragma unroll
                    for (int i = 0; i < 4; i++) {
                        af[nxt][i]  = *(const bf16x8*)&hin[offA[i] + (ks + 2) * 32];
                        bfr[nxt][i] = *(const bf16x8*)&whh_bf[offB[i] + (ks + 2) * 32];
                    }
                }
#pragma unroll
                for (int mi = 0; mi < 4; mi++)
#pragma unroll
                    for (int ni = 0; ni < 4; ni++)
                        acc[mi][ni] = __builtin_amdgcn_mfma_f32_16x16x32_bf16(
                            af[cur][mi], bfr[cur][ni], acc[mi][ni], 0, 0, 0);
            }
        }

        // epilogue: C/D row = q*4+reg, col = l16 (HW-verified); + proj + tanh
#pragma unroll
        for (int mi = 0; mi < 4; mi++) {
#pragma unroll
            for (int r = 0; r < 4; r++) {
                int rl  = wm + mi * 16 + q * 4 + r;
                int tok = tok_sh[rl][t];
                const float* ps = &proj_sh[tok][0];
                bf16_t* orow = hout + (m0 + rl) * HID + n0;
#pragma unroll
                for (int ni = 0; ni < 4; ni++) {
                    float v = acc[mi][ni][r] + ps[ni * 16 + l16];
                    orow[ni * 16 + l16] = (bf16_t)fast_tanh(v);
                }
            }
        }

        if (t < SEN - 1) {
            __threadfence();   // release: push h stores past per-XCD L2
            grid.sync();
            __threadfence();   // acquire: invalidate stale lines before next read
        }
    }
}

// =====================================================================
// FALLBACK PATH: proven R2 per-step kernel (64 launches) — used only if
// the cooperative launch is rejected.
// =====================================================================
#define BM 128
#define BN 64
#define BK 64
#define LDK 72

__global__ __launch_bounds__(256)
void rnn_step(const bf16_t* __restrict__ h_in, const bf16_t* __restrict__ whh,
              const float* __restrict__ proj, const int* __restrict__ x,
              bf16_t* __restrict__ h_out, int t, int first)
{
    __shared__ __align__(16) bf16_t Ash[2][BM][LDK];
    __shared__ __align__(16) bf16_t Bsh[2][BN][LDK];
    __shared__ int tok_sh[BM];

    const int tid = threadIdx.x;
    const int m0 = blockIdx.x * BM;
    const int n0 = blockIdx.y * BN;
    if (tid < BM) tok_sh[tid] = x[(m0 + tid) * SEN + t];

    const int wave = tid >> 6;
    const int lane = tid & 63;
    const int wm   = wave * 32;
    const int q    = lane >> 4;
    const int l16  = lane & 15;

    floatx4 acc[2][4];
#pragma unroll
    for (int i = 0; i < 2; i++)
#pragma unroll
        for (int j = 0; j < 4; j++) acc[i][j] = (floatx4){0.f, 0.f, 0.f, 0.f};

    if (!first) {
#pragma unroll
        for (int it = 0; it < 4; it++) {
            int idx = tid + it * 256, r = idx >> 3, c = (idx & 7) * 8;
            *(uint4*)&Ash[0][r][c] = *(const uint4*)&h_in[(m0 + r) * HID + c];
        }
#pragma unroll
        for (int it = 0; it < 2; it++) {
            int idx = tid + it * 256, r = idx >> 3, c = (idx & 7) * 8;
            *(uint4*)&Bsh[0][r][c] = *(const uint4*)&whh[(n0 + r) * HID + c];
        }
    }
    __syncthreads();

    if (!first) {
        for (int i = 0; i < 16; i++) {
            const int buf = i & 1;
            uint4 pa[4], pb[2];
            const int kk = (i + 1) * BK;
            if (i < 15) {
#pragma unroll
                for (int it = 0; it < 4; it++) {
                    int idx = tid + it * 256, r = idx >> 3, c = (idx & 7) * 8;
                    pa[it] = *(const uint4*)&h_in[(m0 + r) * HID + kk + c];
                }
#pragma unroll
                for (int it = 0; it < 2; it++) {
                    int idx = tid + it * 256, r = idx >> 3, c = (idx & 7) * 8;
                    pb[it] = *(const uint4*)&whh[(n0 + r) * HID + kk + c];
                }
            }
#pragma unroll
            for (int ks = 0; ks < BK; ks += 32) {
                bf16x8 af[2], bfr[4];
#pragma unroll
                for (int mi = 0; mi < 2; mi++)
                    af[mi] = *(const bf16x8*)&Ash[buf][wm + mi * 16 + l16][ks + q * 8];
#pragma unroll
                for (int ni = 0; ni < 4; ni++)
                    bfr[ni] = *(const bf16x8*)&Bsh[buf][ni * 16 + l16][ks + q * 8];
#pragma unroll
                for (int mi = 0; mi < 2; mi++)
#pragma unroll
                    for (int ni = 0; ni < 4; ni++)
                        acc[mi][ni] = __builtin_amdgcn_mfma_f32_16x16x32_bf16(
                            af[mi], bfr[ni], acc[mi][ni], 0, 0, 0);
            }
            if (i < 15) {
#pragma unroll
                for (int it = 0; it < 4; it++) {
                    int idx = tid + it * 256, r = idx >> 3, c = (idx & 7) * 8;
                    *(uint4*)&Ash[1 - buf][r][c] = pa[it];
                }
#pragma unroll
                for (int it = 0; it < 2; it++) {
                    int idx = tid + it * 256, r = idx >> 3, c = (idx & 7) * 8;
                    *(uint4*)&Bsh[1 - buf][r][c] = pb[it];
                }
                __syncthreads();
            }
        }
    }

#pragma unroll
    for (int mi = 0; mi < 2; mi++) {
#pragma unroll
        for (int r = 0; r < 4; r++) {
            int lm = wm + mi * 16 + q * 4 + r;
            int gm = m0 + lm;
            const float* pr = proj + tok_sh[lm] * HID;
#pragma unroll
            for (int ni = 0; ni < 4; ni++) {
                int gn = n0 + ni * 16 + l16;
                float v = acc[mi][ni][r] + pr[gn];
                h_out[gm * HID + gn] = (bf16_t)fast_tanh(v);
            }
        }
    }
}

// ---------------- classifier: out = h @ W_cls^T + b_cls via MFMA (proven R2) ----------------
#define CBM 128
__global__ __launch_bounds__(256)
void classifier_mfma(const bf16_t* __restrict__ h, const bf16_t* __restrict__ wcls,
                     const float* __restrict__ bcls, float* __restrict__ out)
{
    __shared__ __align__(16) bf16_t Ash[CBM][LDK];
    __shared__ __align__(16) bf16_t Bsh[80][LDK];

    const int tid = threadIdx.x;
    const int m0 = blockIdx.x * CBM;
    const int wave = tid >> 6, lane = tid & 63;
    const int wm = wave * 32;
    const int q = lane >> 4, l16 = lane & 15;

    floatx4 acc[2][5];
#pragma unroll
    for (int i = 0; i < 2; i++)
#pragma unroll
        for (int j = 0; j < 5; j++) acc[i][j] = (floatx4){0.f, 0.f, 0.f, 0.f};

    for (int kk = 0; kk < HID; kk += 64) {
#pragma unroll
        for (int it = 0; it < 4; it++) {
            int idx = tid + it * 256, r = idx >> 3, c = (idx & 7) * 8;
            *(uint4*)&Ash[r][c] = *(const uint4*)&h[(m0 + r) * HID + kk + c];
        }
#pragma unroll
        for (int it = 0; it < 3; it++) {
            int idx = tid + it * 256;
            if (idx < 640) {
                int r = idx >> 3, c = (idx & 7) * 8;
                *(uint4*)&Bsh[r][c] = *(const uint4*)&wcls[r * HID + kk + c];
            }
        }
        __syncthreads();
#pragma unroll
        for (int ks = 0; ks < 64; ks += 32) {
            bf16x8 af[2], bfr[5];
#pragma unroll
            for (int mi = 0; mi < 2; mi++)
                af[mi] = *(const bf16x8*)&Ash[wm + mi * 16 + l16][ks + q * 8];
#pragma unroll
            for (int ni = 0; ni < 5; ni++)
                bfr[ni] = *(const bf16x8*)&Bsh[ni * 16 + l16][ks + q * 8];
#pragma unroll
            for (int mi = 0; mi < 2; mi++)
#pragma unroll
                for (int ni = 0; ni < 5; ni++)
                    acc[mi][ni] = __builtin_amdgcn_mfma_f32_16x16x32_bf16(
                        af[mi], bfr[ni], acc[mi][ni], 0, 0, 0);
        }
        __syncthreads();
    }

#pragma unroll
    for (int mi = 0; mi < 2; mi++) {
#pragma unroll
        for (int r = 0; r < 4; r++) {
            int gm = m0 + wm + mi * 16 + q * 4 + r;
#pragma unroll
            for (int ni = 0; ni < 5; ni++) {
                int gn = ni * 16 + l16;
                if (gn < SEN + 1)
                    out[gm * (SEN + 1) + gn] = acc[mi][ni][r] + bcls[gn];
            }
        }
    }
}

extern "C" void kernel_launch(void* const* d_in, const int* in_sizes, int n_in,
                              void* d_out, int out_size, void* d_ws, size_t ws_size,
                              hipStream_t stream)
{
    const int*   x     = (const int*)  d_in[0];
    const float* emb   = (const float*)d_in[1];
    const float* w_ih  = (const float*)d_in[2];
    const float* w_hh  = (const float*)d_in[3];
    const float* w_cls = (const float*)d_in[4];
    const float* b_cls = (const float*)d_in[5];
    float* out = (float*)d_out;

    char* ws = (char*)d_ws;
    bf16_t* whh_bf  = (bf16_t*)ws;                                  // 2 MB
    float*  proj    = (float*)(ws + (2u << 20));                    // 128 KB
    bf16_t* wcls_bf = (bf16_t*)(ws + (2u << 20) + (128u << 10));    // 160 KB
    bf16_t* h0      = (bf16_t*)(ws + (2u << 20) + (288u << 10));    // 4 MB
    bf16_t* h1      = (bf16_t*)(ws + (6u << 20) + (288u << 10));    // 4 MB

    cvt_whh<<<(HID * HID) / 256, 256, 0, stream>>>(w_hh, whh_bf, HID * HID);
    proj_kernel<<<(VOCAB * HID + 255) / 256, 256, 0, stream>>>(emb, w_ih, proj);
    cvt_wcls<<<(80 * HID) / 256, 256, 0, stream>>>(w_cls, wcls_bf);

    // ---- fast path: cooperative persistent kernel ----
    void* args[] = {(void*)&whh_bf, (void*)&proj, (void*)&x, (void*)&h0, (void*)&h1};
    hipError_t ce = hipLaunchCooperativeKernel((void*)rnn_stream, dim3(16, 16),
                                               dim3(128, 1, 1), args, 0, stream);
    if (ce != hipSuccess) {
        (void)hipGetLastError();   // clear sticky error; take proven fallback
        dim3 grid(BATCH / BM, HID / BN);
        bf16_t* bufs[2] = {h0, h1};
        for (int t = 0; t < SEN; t++) {
            bf16_t* hi = bufs[(t + 1) & 1];
            bf16_t* ho = bufs[t & 1];
            rnn_step<<<grid, 256, 0, stream>>>(hi, whh_bf, proj, x, ho, t, t == 0 ? 1 : 0);
        }
    }

    classifier_mfma<<<BATCH / CBM, 256, 0, stream>>>(h1, wcls_bf, b_cls, out);
}

// Round 5
// 782.624 us; speedup vs baseline: 6.1986x; 6.1986x over previous
//
#include <hip/hip_runtime.h>
#include <hip/hip_bf16.h>

#define VOCAB 29
#define VEC   512
#define HID   1024
#define SEN   64
#define BATCH 2048

typedef __bf16 bf16_t;
typedef bf16_t bf16x8 __attribute__((ext_vector_type(8)));
typedef float  floatx4 __attribute__((ext_vector_type(4)));

// ---------------- prep: W_hh fp32 -> bf16 ----------------
__global__ void cvt_whh(const float* __restrict__ w, bf16_t* __restrict__ o, int n) {
    int i = blockIdx.x * blockDim.x + threadIdx.x;
    if (i < n) o[i] = (bf16_t)w[i];
}

// ---------------- prep: W_cls fp32 [65][1024] -> bf16 padded [80][1024] ----------------
__global__ void cvt_wcls(const float* __restrict__ w, bf16_t* __restrict__ o) {
    int i = blockIdx.x * blockDim.x + threadIdx.x;
    if (i >= 80 * HID) return;
    o[i] = (i < 65 * HID) ? (bf16_t)w[i] : (bf16_t)0.0f;
}

// ---------------- prep: proj[v][h] = dot(emb[v], W_ih[h]) (fp32) ----------------
__global__ void proj_kernel(const float* __restrict__ emb, const float* __restrict__ wih,
                            float* __restrict__ proj) {
    int idx = blockIdx.x * blockDim.x + threadIdx.x;
    if (idx >= VOCAB * HID) return;
    int v = idx / HID, h = idx % HID;
    const float* e = emb + v * VEC;
    const float* w = wih + h * VEC;
    float s = 0.f;
    for (int k = 0; k < VEC; k += 4) {
        float4 ev = *(const float4*)(e + k);
        float4 wv = *(const float4*)(w + k);
        s += ev.x * wv.x + ev.y * wv.y + ev.z * wv.z + ev.w * wv.w;
    }
    proj[idx] = s;
}

// exact identity tanh(x) = 1 - 2/(exp(2x)+1); fp32 rounding error << bf16 ulp
__device__ __forceinline__ float fast_tanh(float x) {
    float e = __expf(2.0f * x);
    return 1.0f - 2.0f / (e + 1.0f);
}

// async global->LDS 16B copy. LDS dest: wave-uniform base + lane*16 (HW rule).
// Integer-cast route (CK-style): AS1 keeps the 64-bit VA; AS3 takes low 32 bits
// (generic shared VA carries the LDS offset in its low dword).
__device__ __forceinline__ void load16_to_lds(const bf16_t* g, bf16_t* l) {
    auto gp = reinterpret_cast<const __attribute__((address_space(1))) unsigned int*>(
        reinterpret_cast<uintptr_t>(g));
    auto lp = reinterpret_cast<__attribute__((address_space(3))) unsigned int*>(
        static_cast<unsigned int>(reinterpret_cast<uintptr_t>(l)));
    __builtin_amdgcn_global_load_lds(gp, lp, 16, 0, 0);
}

// ---------------- RNN step: h_out = tanh(proj[x[:,t]] + h_in @ W_hh^T) ----------------
// BM=128, BN=64, grid (16,16)=256 blocks (1/CU), 256 thr = 4 waves, wave tile 32x64.
// Staging: global_load_lds(16B) direct to LDS, XOR-swizzled chunks (phys = glob ^ (row&7))
// so dests stay lane-linear while ds_read_b128 frag reads land 2-way conflicts (free).
// Double buffer, loads for tile i+1 issued BEFORE compute of tile i, one barrier/iter.
#define BM 128
#define BN 64
#define BK 64

__global__ __launch_bounds__(256)
void rnn_step(const bf16_t* __restrict__ h_in, const bf16_t* __restrict__ whh,
              const float* __restrict__ proj, const int* __restrict__ x,
              bf16_t* __restrict__ h_out, int t, int first)
{
    __shared__ __align__(16) bf16_t Ash[2][BM][BK];   // 32 KB
    __shared__ __align__(16) bf16_t Bsh[2][BN][BK];   // 16 KB
    __shared__ int tok_sh[BM];

    const int tid  = threadIdx.x;
    const int m0   = blockIdx.x * BM;
    const int n0   = blockIdx.y * BN;
    const int wave = tid >> 6;
    const int lane = tid & 63;
    const int wm   = wave * 32;        // 4 waves split m
    const int q    = lane >> 4;
    const int l16  = lane & 15;

    if (tid < BM) tok_sh[tid] = x[(m0 + tid) * SEN + t];

    // Per-lane staging sources (constant across K-iters; advance by BK elements).
    // Chunk id c = it*256 + wave*64 + lane; row r=c>>3, phys chunk p=c&7,
    // global chunk g = p ^ (r&7). LDS dest (wave-uniform) = buf base + (c - lane)*8 elems.
    const bf16_t* srcA[4];
    const bf16_t* srcB[2];
    int dstA[4], dstB[2];
#pragma unroll
    for (int it = 0; it < 4; it++) {
        int c = it * 256 + wave * 64 + lane;
        int r = c >> 3, p = c & 7, g = p ^ (r & 7);
        srcA[it] = h_in + (m0 + r) * HID + g * 8;
        dstA[it] = (it * 256 + wave * 64) * 8;
    }
#pragma unroll
    for (int it = 0; it < 2; it++) {
        int c = it * 256 + wave * 64 + lane;
        int r = c >> 3, p = c & 7, g = p ^ (r & 7);
        srcB[it] = whh + (n0 + r) * HID + g * 8;
        dstB[it] = (it * 256 + wave * 64) * 8;
    }

    floatx4 acc[2][4];
#pragma unroll
    for (int i = 0; i < 2; i++)
#pragma unroll
        for (int j = 0; j < 4; j++) acc[i][j] = (floatx4){0.f, 0.f, 0.f, 0.f};

    if (!first) {
        // stage tile 0 -> buf 0 (async)
#pragma unroll
        for (int it = 0; it < 4; it++) load16_to_lds(srcA[it], &Ash[0][0][0] + dstA[it]);
#pragma unroll
        for (int it = 0; it < 2; it++) load16_to_lds(srcB[it], &Bsh[0][0][0] + dstB[it]);
    }
    __syncthreads();   // drains tile-0 DMA + covers tok_sh (all paths)

    if (!first) {
        for (int i = 0; i < 16; i++) {
            const int buf = i & 1;
            if (i < 15) {
                // issue next tile's DMA BEFORE compute: cover = the whole iteration
                const int koff = (i + 1) * BK;
#pragma unroll
                for (int it = 0; it < 4; it++)
                    load16_to_lds(srcA[it] + koff, &Ash[1 - buf][0][0] + dstA[it]);
#pragma unroll
                for (int it = 0; it < 2; it++)
                    load16_to_lds(srcB[it] + koff, &Bsh[1 - buf][0][0] + dstB[it]);
            }
#pragma unroll
            for (int ks = 0; ks < BK; ks += 32) {
                // phys chunk for this (ks,q) — row&7 == l16&7 for every frag row
                const int pq = (((ks >> 3) + q) ^ (l16 & 7)) * 8;
                bf16x8 af[2], bfr[4];
                af[0]  = *(const bf16x8*)&Ash[buf][wm + l16][pq];
                af[1]  = *(const bf16x8*)&Ash[buf][wm + 16 + l16][pq];
                bfr[0] = *(const bf16x8*)&Bsh[buf][l16][pq];
                bfr[1] = *(const bf16x8*)&Bsh[buf][16 + l16][pq];
                bfr[2] = *(const bf16x8*)&Bsh[buf][32 + l16][pq];
                bfr[3] = *(const bf16x8*)&Bsh[buf][48 + l16][pq];
#pragma unroll
                for (int mi = 0; mi < 2; mi++)
#pragma unroll
                    for (int ni = 0; ni < 4; ni++)
                        acc[mi][ni] = __builtin_amdgcn_mfma_f32_16x16x32_bf16(
                            af[mi], bfr[ni], acc[mi][ni], 0, 0, 0);
            }
            if (i < 15) __syncthreads();   // drains DMA (vmcnt0) + guards buffer swap
        }
    }

    // epilogue: C/D row = q*4+reg, col = l16 (HW-verified); + proj + tanh
#pragma unroll
    for (int mi = 0; mi < 2; mi++) {
#pragma unroll
        for (int r = 0; r < 4; r++) {
            int lm = wm + mi * 16 + q * 4 + r;
            int gm = m0 + lm;
            const float* pr = proj + tok_sh[lm] * HID;
#pragma unroll
            for (int ni = 0; ni < 4; ni++) {
                int gn = n0 + ni * 16 + l16;
                float v = acc[mi][ni][r] + pr[gn];
                h_out[gm * HID + gn] = (bf16_t)fast_tanh(v);
            }
        }
    }
}

// ---------------- classifier: out = h @ W_cls^T + b_cls via MFMA (proven R2) ----------------
#define CBM 128
#define CLDK 72
__global__ __launch_bounds__(256)
void classifier_mfma(const bf16_t* __restrict__ h, const bf16_t* __restrict__ wcls,
                     const float* __restrict__ bcls, float* __restrict__ out)
{
    __shared__ __align__(16) bf16_t Ash[CBM][CLDK];
    __shared__ __align__(16) bf16_t Bsh[80][CLDK];

    const int tid = threadIdx.x;
    const int m0 = blockIdx.x * CBM;
    const int wave = tid >> 6, lane = tid & 63;
    const int wm = wave * 32;
    const int q = lane >> 4, l16 = lane & 15;

    floatx4 acc[2][5];
#pragma unroll
    for (int i = 0; i < 2; i++)
#pragma unroll
        for (int j = 0; j < 5; j++) acc[i][j] = (floatx4){0.f, 0.f, 0.f, 0.f};

    for (int kk = 0; kk < HID; kk += 64) {
#pragma unroll
        for (int it = 0; it < 4; it++) {
            int idx = tid + it * 256, r = idx >> 3, c = (idx & 7) * 8;
            *(uint4*)&Ash[r][c] = *(const uint4*)&h[(m0 + r) * HID + kk + c];
        }
#pragma unroll
        for (int it = 0; it < 3; it++) {
            int idx = tid + it * 256;
            if (idx < 640) {
                int r = idx >> 3, c = (idx & 7) * 8;
                *(uint4*)&Bsh[r][c] = *(const uint4*)&wcls[r * HID + kk + c];
            }
        }
        __syncthreads();
#pragma unroll
        for (int ks = 0; ks < 64; ks += 32) {
            bf16x8 af[2], bfr[5];
#pragma unroll
            for (int mi = 0; mi < 2; mi++)
                af[mi] = *(const bf16x8*)&Ash[wm + mi * 16 + l16][ks + q * 8];
#pragma unroll
            for (int ni = 0; ni < 5; ni++)
                bfr[ni] = *(const bf16x8*)&Bsh[ni * 16 + l16][ks + q * 8];
#pragma unroll
            for (int mi = 0; mi < 2; mi++)
#pragma unroll
                for (int ni = 0; ni < 5; ni++)
                    acc[mi][ni] = __builtin_amdgcn_mfma_f32_16x16x32_bf16(
                        af[mi], bfr[ni], acc[mi][ni], 0, 0, 0);
        }
        __syncthreads();
    }

#pragma unroll
    for (int mi = 0; mi < 2; mi++) {
#pragma unroll
        for (int r = 0; r < 4; r++) {
            int gm = m0 + wm + mi * 16 + q * 4 + r;
#pragma unroll
            for (int ni = 0; ni < 5; ni++) {
                int gn = ni * 16 + l16;
                if (gn < SEN + 1)
                    out[gm * (SEN + 1) + gn] = acc[mi][ni][r] + bcls[gn];
            }
        }
    }
}

extern "C" void kernel_launch(void* const* d_in, const int* in_sizes, int n_in,
                              void* d_out, int out_size, void* d_ws, size_t ws_size,
                              hipStream_t stream)
{
    const int*   x     = (const int*)  d_in[0];
    const float* emb   = (const float*)d_in[1];
    const float* w_ih  = (const float*)d_in[2];
    const float* w_hh  = (const float*)d_in[3];
    const float* w_cls = (const float*)d_in[4];
    const float* b_cls = (const float*)d_in[5];
    float* out = (float*)d_out;

    char* ws = (char*)d_ws;
    bf16_t* whh_bf  = (bf16_t*)ws;                                  // 2 MB
    float*  proj    = (float*)(ws + (2u << 20));                    // 128 KB
    bf16_t* wcls_bf = (bf16_t*)(ws + (2u << 20) + (128u << 10));    // 160 KB
    bf16_t* h0      = (bf16_t*)(ws + (2u << 20) + (288u << 10));    // 4 MB
    bf16_t* h1      = (bf16_t*)(ws + (6u << 20) + (288u << 10));    // 4 MB

    cvt_whh<<<(HID * HID) / 256, 256, 0, stream>>>(w_hh, whh_bf, HID * HID);
    proj_kernel<<<(VOCAB * HID + 255) / 256, 256, 0, stream>>>(emb, w_ih, proj);
    cvt_wcls<<<(80 * HID) / 256, 256, 0, stream>>>(w_cls, wcls_bf);

    dim3 grid(BATCH / BM, HID / BN);   // (16,16) = 256 blocks
    bf16_t* bufs[2] = {h0, h1};
    for (int t = 0; t < SEN; t++) {
        bf16_t* hi = bufs[(t + 1) & 1];   // ignored when t==0 (first=1)
        bf16_t* ho = bufs[t & 1];
        rnn_step<<<grid, 256, 0, stream>>>(hi, whh_bf, proj, x, ho, t, t == 0 ? 1 : 0);
    }
    classifier_mfma<<<BATCH / CBM, 256, 0, stream>>>(bufs[1], wcls_bf, b_cls, out);
}